// Round 2
// baseline (18465.509 us; speedup 1.0000x reference)
//
#include <hip/hip_runtime.h>
#include <hip/hip_bf16.h>

// LSTM (1 layer): B=64, S=512, I=H=1024. Output = final cell state c [1,64,1024] fp32.
// fp32-accurate GEMMs via bf16 split-2 (3-product) MFMA.
//   x_proj: m97-style 128x128-tile GEMM with global_load_lds (chunked over S by ws_size).
//   recurrence: PERSISTENT kernel per chunk — 64 blocks (1/CU), manual grid barrier
//   per step (agent-scope release/acquire for cross-XCD h visibility), w_hh hi-plane
//   B-frags register-resident, c register-resident.

#define B_ 64
#define S_ 512
#define I_ 1024
#define H_ 1024
#define G_ 4096  // 4*H
#define NBLK 64  // persistent grid

typedef __attribute__((ext_vector_type(8))) short bf16x8;
typedef __attribute__((ext_vector_type(4))) float f32x4;

__device__ __forceinline__ unsigned short f2bf(float f) {
  unsigned u = __float_as_uint(f);
  u += 0x7FFFu + ((u >> 16) & 1u);
  return (unsigned short)(u >> 16);
}
__device__ __forceinline__ float bf2f(unsigned short b) {
  return __uint_as_float(((unsigned)b) << 16);
}
__device__ __forceinline__ void gld16(const void* g, void* l) {
  __builtin_amdgcn_global_load_lds((const __attribute__((address_space(1))) void*)g,
                                   (__attribute__((address_space(3))) void*)l, 16, 0, 0);
}
__device__ __forceinline__ f32x4 mfma16(bf16x8 a, bf16x8 b, f32x4 c) {
  return __builtin_amdgcn_mfma_f32_16x16x32_bf16(a, b, c, 0, 0, 0);
}

// ---------------- split fp32 matrix -> bf16 hi/lo planes ----------------
__global__ void split_mat(const float* __restrict__ src, unsigned short* __restrict__ hi,
                          unsigned short* __restrict__ lo, int n4) {
  int idx = blockIdx.x * 256 + threadIdx.x;
  if (idx >= n4) return;
  float4 v = ((const float4*)src)[idx];
  ushort4 h, l;
  h.x = f2bf(v.x); l.x = f2bf(v.x - bf2f(h.x));
  h.y = f2bf(v.y); l.y = f2bf(v.y - bf2f(h.y));
  h.z = f2bf(v.z); l.z = f2bf(v.z - bf2f(h.z));
  h.w = f2bf(v.w); l.w = f2bf(v.w - bf2f(h.w));
  ((ushort4*)hi)[idx] = h;
  ((ushort4*)lo)[idx] = l;
}

// ---------------- bias = b_ih + b_hh ; h/c init ; barrier counter init ----------------
__global__ void prep(const float* __restrict__ h0, const float* __restrict__ c0,
                     const float* __restrict__ b_ih, const float* __restrict__ b_hh,
                     unsigned short* __restrict__ hhi0, unsigned short* __restrict__ hlo0,
                     float* __restrict__ c, float* __restrict__ bias,
                     unsigned* __restrict__ cnt) {
  int idx = blockIdx.x * 256 + threadIdx.x;
  if (idx == 0) *cnt = 0u;
  if (idx < G_) bias[idx] = b_ih[idx] + b_hh[idx];
  if (idx < B_ * H_) {
    int k = idx & (H_ - 1);
    float v = h0[k];
    unsigned short hh = f2bf(v);
    hhi0[idx] = hh;
    hlo0[idx] = f2bf(v - bf2f(hh));
    c[idx] = c0[k];
  }
}

// ---------------- split x chunk into A-matrix layout [m=(t_local*64+b)][i] ----------------
__global__ void split_x(const float* __restrict__ x, unsigned short* __restrict__ xhi,
                        unsigned short* __restrict__ xlo, int t0) {
  int idx = blockIdx.x * 256 + threadIdx.x;
  int i4 = (idx & 255) * 4;
  int m = idx >> 8;
  int b = m & 63, tl = m >> 6;
  float4 v = *(const float4*)(x + ((size_t)b * S_ + (size_t)(t0 + tl)) * I_ + i4);
  ushort4 h, l;
  h.x = f2bf(v.x); l.x = f2bf(v.x - bf2f(h.x));
  h.y = f2bf(v.y); l.y = f2bf(v.y - bf2f(h.y));
  h.z = f2bf(v.z); l.z = f2bf(v.z - bf2f(h.z));
  h.w = f2bf(v.w); l.w = f2bf(v.w - bf2f(h.w));
  *(ushort4*)(xhi + (size_t)m * I_ + i4) = h;
  *(ushort4*)(xlo + (size_t)m * I_ + i4) = l;
}

// ---------------- x_proj GEMM: [Tc*64 x 1024] * [1024 x 4096]^T (+bias) ----------------
__global__ __launch_bounds__(256) void xproj_gemm(
    const unsigned short* __restrict__ xhi, const unsigned short* __restrict__ xlo,
    const unsigned short* __restrict__ whi, const unsigned short* __restrict__ wlo,
    const float* __restrict__ bias, float* __restrict__ xp) {
  __shared__ unsigned short Ah[128 * 32], Al[128 * 32], Bh[128 * 32], Bl[128 * 32];
  const int tid = threadIdx.x, lane = tid & 63, wv = tid >> 6;
  const int l15 = lane & 15, kg = lane >> 4;
  const int wm = wv >> 1, wn = wv & 1;
  const size_t aRow0 = (size_t)blockIdx.y * 128, bRow0 = (size_t)blockIdx.x * 128;

  f32x4 acc[4][4];
#pragma unroll
  for (int a = 0; a < 4; ++a)
#pragma unroll
    for (int b2 = 0; b2 < 4; ++b2)
#pragma unroll
      for (int e = 0; e < 4; ++e) acc[a][b2][e] = 0.f;

  const int r0 = wv * 2;
  const int rowIn = lane >> 2;
  const int kb = (lane & 3) * 16;

  for (int kt = 0; kt < 32; ++kt) {
#pragma unroll
    for (int j = 0; j < 2; ++j) {
      const int ld = (r0 + j) * 1024;
      const int row = (r0 + j) * 16 + rowIn;
      const size_t ka = (size_t)kt * 64 + kb;
      gld16((const char*)xhi + (aRow0 + row) * 2048 + ka, (char*)Ah + ld);
      gld16((const char*)xlo + (aRow0 + row) * 2048 + ka, (char*)Al + ld);
      gld16((const char*)whi + (bRow0 + row) * 2048 + ka, (char*)Bh + ld);
      gld16((const char*)wlo + (bRow0 + row) * 2048 + ka, (char*)Bl + ld);
    }
    __syncthreads();
    bf16x8 ah[4], al[4], bh[4], bl[4];
#pragma unroll
    for (int f = 0; f < 4; ++f) {
      ah[f] = *(const bf16x8*)&Ah[(wm * 64 + f * 16 + l15) * 32 + kg * 8];
      al[f] = *(const bf16x8*)&Al[(wm * 64 + f * 16 + l15) * 32 + kg * 8];
      bh[f] = *(const bf16x8*)&Bh[(wn * 64 + f * 16 + l15) * 32 + kg * 8];
      bl[f] = *(const bf16x8*)&Bl[(wn * 64 + f * 16 + l15) * 32 + kg * 8];
    }
#pragma unroll
    for (int mf = 0; mf < 4; ++mf)
#pragma unroll
      for (int nf = 0; nf < 4; ++nf) {
        acc[mf][nf] = mfma16(ah[mf], bh[nf], acc[mf][nf]);
        acc[mf][nf] = mfma16(al[mf], bh[nf], acc[mf][nf]);
        acc[mf][nf] = mfma16(ah[mf], bl[nf], acc[mf][nf]);
      }
    __syncthreads();
  }
#pragma unroll
  for (int nf = 0; nf < 4; ++nf) {
    const int col = (int)bRow0 + wn * 64 + nf * 16 + l15;
    const float bv = bias[col];
#pragma unroll
    for (int mf = 0; mf < 4; ++mf)
#pragma unroll
      for (int i = 0; i < 4; ++i) {
        const size_t m = aRow0 + (size_t)(wm * 64 + mf * 16 + kg * 4 + i);
        xp[m * G_ + col] = acc[mf][nf][i] + bv;
      }
  }
}

// ---------------- persistent recurrence: Tc steps, grid barrier per step ----------------
// 64 blocks x 1024 thr (16 waves = 4 gates x 4 K-slices). Block nt owns H-cols
// nt*16..+16 (all 4 gates, all 64 batches). c lives in a register per thread.
__global__ __launch_bounds__(1024) void lstm_persist(
    const float* __restrict__ xp_c,
    unsigned short* __restrict__ h_hi0, unsigned short* __restrict__ h_lo0,
    unsigned short* __restrict__ h_hi1, unsigned short* __restrict__ h_lo1,
    float* __restrict__ c,
    const unsigned short* __restrict__ whi, const unsigned short* __restrict__ wlo,
    float* __restrict__ out, unsigned* __restrict__ cnt, int t0, int Tc) {
  __shared__ float gl[16 * 64 * 16];  // [kh*4+g][batch][j] : 64 KB
  const int tid = threadIdx.x, lane = tid & 63, wv = tid >> 6;
  const int g = wv & 3, kh = wv >> 2;
  const int l15 = lane & 15, kg = lane >> 4;
  const int nt = blockIdx.x;

  // w_hh fragments: hi plane register-resident, lo plane streamed per step
  const int wrow = g * 1024 + nt * 16 + l15;
  const unsigned short* bp_h = whi + (size_t)wrow * H_ + kh * 256 + kg * 8;
  const unsigned short* bp_l = wlo + (size_t)wrow * H_ + kh * 256 + kg * 8;
  bf16x8 bh_r[8];
#pragma unroll
  for (int kt = 0; kt < 8; ++kt) bh_r[kt] = *(const bf16x8*)(bp_h + kt * 32);

  // elementwise identity: thread -> (batch eb, col j within block's 16)
  const int eb = tid >> 4, ej = tid & 15;
  const int col = nt * 16 + ej;
  const int ci = eb * H_ + col;
  float creg = c[ci];

  const int aoff = kh * 256 + kg * 8;

  for (int tl = 0; tl < Tc; ++tl) {
    const int t = t0 + tl;
    const unsigned short* hi_in = (t & 1) ? h_hi1 : h_hi0;
    const unsigned short* lo_in = (t & 1) ? h_lo1 : h_lo0;
    unsigned short* hi_out = (t & 1) ? h_hi0 : h_hi1;
    unsigned short* lo_out = (t & 1) ? h_lo0 : h_lo1;

    // issue xp loads early; consumed after the MFMA phase
    const float* xpr = xp_c + ((size_t)tl * B_ + eb) * G_;
    float xq0 = xpr[col], xq1 = xpr[col + 1024], xq2 = xpr[col + 2048], xq3 = xpr[col + 3072];

    f32x4 acc[4];
#pragma unroll
    for (int m = 0; m < 4; ++m)
#pragma unroll
      for (int e = 0; e < 4; ++e) acc[m][e] = 0.f;

    const unsigned short* ap_h = hi_in + (size_t)l15 * H_ + aoff;
    const unsigned short* ap_l = lo_in + (size_t)l15 * H_ + aoff;
#pragma unroll
    for (int kt = 0; kt < 8; ++kt) {
      const bf16x8 bl = *(const bf16x8*)(bp_l + kt * 32);
#pragma unroll
      for (int mf = 0; mf < 4; ++mf) {
        const bf16x8 ah = *(const bf16x8*)(ap_h + (size_t)mf * 16 * H_ + kt * 32);
        const bf16x8 al = *(const bf16x8*)(ap_l + (size_t)mf * 16 * H_ + kt * 32);
        acc[mf] = mfma16(ah, bh_r[kt], acc[mf]);
        acc[mf] = mfma16(al, bh_r[kt], acc[mf]);
        acc[mf] = mfma16(ah, bl, acc[mf]);
      }
    }
#pragma unroll
    for (int mf = 0; mf < 4; ++mf)
#pragma unroll
      for (int i = 0; i < 4; ++i)
        gl[(wv * 64 + mf * 16 + kg * 4 + i) * 16 + l15] = acc[mf][i];
    __syncthreads();

    float xs[4];
#pragma unroll
    for (int gg = 0; gg < 4; ++gg) {
      float s = 0.f;
#pragma unroll
      for (int k2 = 0; k2 < 4; ++k2) s += gl[((k2 * 4 + gg) * 64 + eb) * 16 + ej];
      xs[gg] = s;
    }
    const float xi = xs[0] + xq0;
    const float xf = xs[1] + xq1;
    const float xg = xs[2] + xq2;
    const float xo = xs[3] + xq3;
    const float ig = 1.f / (1.f + __expf(-xi));
    const float fg = 1.f / (1.f + __expf(-xf));
    const float gt = tanhf(xg);
    const float og = 1.f / (1.f + __expf(-xo));
    creg = fg * creg + ig * gt;
    const float hn = og * tanhf(creg);
    const unsigned short hh = f2bf(hn);
    hi_out[ci] = hh;
    lo_out[ci] = f2bf(hn - bf2f(hh));
    if (t == S_ - 1) out[ci] = creg;

    // ---- grid barrier: release h writes, wait all 64 blocks, acquire ----
    __syncthreads();  // drains this block's stores (vmcnt 0 before s_barrier)
    if (tid == 0) {
      __hip_atomic_fetch_add(cnt, 1u, __ATOMIC_RELEASE, __HIP_MEMORY_SCOPE_AGENT);
      const unsigned tgt = (unsigned)(t + 1) * (unsigned)NBLK;
      while (__hip_atomic_load(cnt, __ATOMIC_RELAXED, __HIP_MEMORY_SCOPE_AGENT) < tgt)
        __builtin_amdgcn_s_sleep(1);
      (void)__hip_atomic_load(cnt, __ATOMIC_ACQUIRE, __HIP_MEMORY_SCOPE_AGENT);
    }
    __syncthreads();
  }
  c[ci] = creg;
}

extern "C" void kernel_launch(void* const* d_in, const int* in_sizes, int n_in,
                              void* d_out, int out_size, void* d_ws, size_t ws_size,
                              hipStream_t stream) {
  const float* x = (const float*)d_in[0];
  const float* h0 = (const float*)d_in[1];
  const float* c0 = (const float*)d_in[2];
  const float* w_ih = (const float*)d_in[3];
  const float* w_hh = (const float*)d_in[4];
  const float* b_ih = (const float*)d_in[5];
  const float* b_hh = (const float*)d_in[6];
  float* out = (float*)d_out;

  char* p = (char*)d_ws;
  auto carve = [&](size_t bytes) {
    char* r = p;
    p += (bytes + 255) & ~(size_t)255;
    return r;
  };
  const size_t wBytes = (size_t)G_ * H_ * 2;  // 8 MB per plane
  unsigned short* wih_hi = (unsigned short*)carve(wBytes);
  unsigned short* wih_lo = (unsigned short*)carve(wBytes);
  unsigned short* whh_hi = (unsigned short*)carve(wBytes);
  unsigned short* whh_lo = (unsigned short*)carve(wBytes);
  float* bias = (float*)carve((size_t)G_ * 4);
  unsigned short* hhi0 = (unsigned short*)carve((size_t)B_ * H_ * 2);
  unsigned short* hhi1 = (unsigned short*)carve((size_t)B_ * H_ * 2);
  unsigned short* hlo0 = (unsigned short*)carve((size_t)B_ * H_ * 2);
  unsigned short* hlo1 = (unsigned short*)carve((size_t)B_ * H_ * 2);
  float* cbuf = (float*)carve((size_t)B_ * H_ * 4);
  unsigned* cnt = (unsigned*)carve(256);
  const size_t fixed = (size_t)(p - (char*)d_ws);

  const size_t per_t = (size_t)B_ * I_ * 2 * 2 + (size_t)B_ * G_ * 4 + 1024;
  long long Tl = 2;
  if (ws_size > fixed) Tl = (long long)((ws_size - fixed) / per_t);
  int T = (int)(Tl > S_ ? S_ : Tl);
  T &= ~1;
  if (T < 2) T = 2;
  unsigned short* xhi = (unsigned short*)carve((size_t)T * B_ * I_ * 2);
  unsigned short* xlo = (unsigned short*)carve((size_t)T * B_ * I_ * 2);
  float* xp = (float*)carve((size_t)T * B_ * G_ * 4);

  split_mat<<<(G_ * H_ / 4 + 255) / 256, 256, 0, stream>>>(w_ih, wih_hi, wih_lo, G_ * H_ / 4);
  split_mat<<<(G_ * H_ / 4 + 255) / 256, 256, 0, stream>>>(w_hh, whh_hi, whh_lo, G_ * H_ / 4);
  prep<<<(B_ * H_ + 255) / 256, 256, 0, stream>>>(h0, c0, b_ih, b_hh, hhi0, hlo0, cbuf, bias,
                                                  cnt);

  int t0 = 0;
  while (t0 < S_) {
    const int Tc = (S_ - t0 < T) ? (S_ - t0) : T;
    split_x<<<Tc * B_ * I_ / 4 / 256, 256, 0, stream>>>(x, xhi, xlo, t0);
    xproj_gemm<<<dim3(G_ / 128, Tc * B_ / 128), 256, 0, stream>>>(xhi, xlo, wih_hi, wih_lo,
                                                                  bias, xp);
    lstm_persist<<<NBLK, 1024, 0, stream>>>(xp, hhi0, hlo0, hhi1, hlo1, cbuf, whh_hi, whh_lo,
                                            out, cnt, t0, Tc);
    t0 += Tc;
  }
}